// Round 1
// baseline (7422.587 us; speedup 1.0000x reference)
//
#include <hip/hip_runtime.h>
#include <math.h>

#define NG 8
#define C96 96
#define NMID 48
#define HW 56
#define PIX 3136      // 56*56
#define GHW 25088     // 8*3136
#define CIN 768       // 96*8
#define NPIXT 9633792 // 4*96*8*3136
#define BN_N 100352   // 4*8*3136

// ---------- group math (matches reference _comp/_inv/_PERM) ----------
__device__ __forceinline__ int d_comp(int a, int b){
  int m1=a>>2, r1=a&3, m2=b>>2, r2=b&3;
  int m=(m1+m2)&1;
  int r = (m2==0) ? (r1+r2) : (r2-r1);
  r = (r+4)&3;
  return 4*m+r;
}
__device__ __forceinline__ int d_inv(int a){ return (a>>2) ? a : ((4-(a&3))&3); }
__device__ __forceinline__ int d_perm(int h, int g){ return d_comp(d_inv(h), g); }

// spatial_transform: K' = rot90^r( flip_x^m (K) ); source index of (dy,dx)
__device__ __forceinline__ void d_src(int h, int dy, int dx, int n, int* sy, int* sx){
  int r=h&3, m=h>>2, e=n-1;
  int y,x;
  if(r==0){y=dy; x=dx;}
  else if(r==1){y=dx; x=e-dy;}
  else if(r==2){y=e-dy; x=e-dx;}
  else {y=e-dx; x=dy;}
  if(m) x = e-x;
  *sy=y; *sx=x;
}

// ---------- BN stats: per-channel mean/var over (B,G,H,W) ----------
__global__ void k_bn_stats(const float* __restrict__ in, float* __restrict__ stats){
  __shared__ float sm[16];
  int c = blockIdx.x;
  float s=0.f, s2=0.f;
  for (int b=0;b<4;b++){
    const float4* p = (const float4*)(in + ((size_t)(b*C96 + c))*GHW);
    for (int i=threadIdx.x; i<GHW/4; i+=blockDim.x){
      float4 v = p[i];
      s  += v.x+v.y+v.z+v.w;
      s2 += v.x*v.x+v.y*v.y+v.z*v.z+v.w*v.w;
    }
  }
  #pragma unroll
  for (int off=32; off>0; off>>=1){ s += __shfl_down(s,off); s2 += __shfl_down(s2,off); }
  int lane=threadIdx.x&63, wid=threadIdx.x>>6;
  if(lane==0){ sm[wid]=s; sm[8+wid]=s2; }
  __syncthreads();
  if(threadIdx.x==0){
    float a=0.f,b2=0.f; int nw = blockDim.x>>6;
    for(int i=0;i<nw;i++){ a+=sm[i]; b2+=sm[8+i]; }
    float mean = a/(float)BN_N;
    stats[c]=mean;
    stats[C96+c]=b2/(float)BN_N - mean*mean;
  }
}

// ---------- BN apply + ReLU (elementwise, float4) ----------
__global__ void k_bn_relu(const float4* __restrict__ in, const float* __restrict__ stats,
                          const float* __restrict__ gamma, const float* __restrict__ beta,
                          float4* __restrict__ outv){
  int i = blockIdx.x*blockDim.x + threadIdx.x;
  if (i >= NPIXT/4) return;
  int c = (i / (GHW/4)) % C96;
  float mean = stats[c], var = stats[C96+c];
  float sc = gamma[c]*rsqrtf(var + 2e-5f);
  float sh = beta[c] - mean*sc;
  float4 v = in[i];
  float4 o;
  o.x = fmaxf(fmaf(v.x,sc,sh), 0.f);
  o.y = fmaxf(fmaf(v.y,sc,sh), 0.f);
  o.z = fmaxf(fmaf(v.z,sc,sh), 0.f);
  o.w = fmaxf(fmaf(v.w,sc,sh), 0.f);
  outv[i]=o;
}

// ---------- s[b,c,g] = mean_{H,W} ----------
__global__ void k_chan_stats(const float* __restrict__ t, float* __restrict__ s){
  __shared__ float sm[2];
  int bcg = blockIdx.x;
  const float4* p = (const float4*)(t + (size_t)bcg*PIX);
  float acc=0.f;
  for (int i=threadIdx.x; i<PIX/4; i+=blockDim.x){ float4 v=p[i]; acc += v.x+v.y+v.z+v.w; }
  #pragma unroll
  for(int off=32;off>0;off>>=1) acc += __shfl_down(acc,off);
  if((threadIdx.x&63)==0) sm[threadIdx.x>>6]=acc;
  __syncthreads();
  if(threadIdx.x==0) s[bcg] = (sm[0]+sm[1])/(float)PIX;
}

// ---------- channel attention stage 1: t[b,m,o] = relu(sum_{c,g} W1[m,c,PERM[o][g]] s[b,c,g]) ----------
__global__ void k_ca1(const float* __restrict__ s, const float* __restrict__ W1, float* __restrict__ t){
  __shared__ float sl[CIN];
  int b = blockIdx.x;
  for (int i=threadIdx.x;i<CIN;i+=blockDim.x) sl[i]=s[b*CIN+i];
  __syncthreads();
  int m = threadIdx.x>>3, o = threadIdx.x&7;
  int pg[8];
  #pragma unroll
  for(int g=0;g<8;g++) pg[g]=d_perm(o,g);
  float acc=0.f;
  for(int c=0;c<C96;c++){
    #pragma unroll
    for(int g=0;g<8;g++) acc += W1[(m*C96+c)*8+pg[g]] * sl[c*8+g];
  }
  t[(b*NMID+m)*8+o] = fmaxf(acc,0.f);
}

// ---------- channel attention stage 2: a[b,c,o] = sigmoid(sum_{m,g} W2[c,m,PERM[o][g]] t[b,m,g]) ----------
__global__ void k_ca2(const float* __restrict__ t, const float* __restrict__ W2, float* __restrict__ a){
  __shared__ float tl[NMID*8];
  int b=blockIdx.x;
  for(int i=threadIdx.x;i<NMID*8;i+=blockDim.x) tl[i]=t[b*NMID*8+i];
  __syncthreads();
  int c=threadIdx.x>>3, o=threadIdx.x&7;
  int pg[8];
  #pragma unroll
  for(int g=0;g<8;g++) pg[g]=d_perm(o,g);
  float acc=0.f;
  for(int m=0;m<NMID;m++){
    #pragma unroll
    for(int g=0;g<8;g++) acc += W2[(c*NMID+m)*8+pg[g]] * tl[m*8+g];
  }
  a[(b*C96+c)*8+o] = 1.f/(1.f+__expf(-acc));
}

// ---------- spatial pool: p[b,{mean,max},g,y,x] over c ----------
__global__ void k_sp_pool(const float* __restrict__ t, float* __restrict__ p){
  int pix = blockIdx.x*blockDim.x+threadIdx.x;
  if(pix>=PIX) return;
  int bg = blockIdx.y; int b=bg>>3, g=bg&7;
  const float* q = t + (size_t)b*CIN*PIX + g*PIX + pix;
  float s=0.f, mx=-1e30f;
  for(int c=0;c<C96;c++){ float v = q[(size_t)c*8*PIX]; s+=v; mx=fmaxf(mx,v); }
  p[((b*2+0)*8+g)*PIX+pix] = s/(float)C96;
  p[((b*2+1)*8+g)*PIX+pix] = mx;
}

// ---------- spatial attention group conv 7x7 (Ni=2, No=1) + sigmoid ----------
__global__ void k_sp_conv(const float* __restrict__ p, const float* __restrict__ Wsp, float* __restrict__ asp){
  __shared__ float wl[2*8*49];
  int bh = blockIdx.y; int b=bh>>3, h=bh&7;
  for(int idx=threadIdx.x; idx<784; idx+=blockDim.x){
    int i = idx/392; int rem = idx-i*392;
    int g = rem/49; int kk = rem-g*49;
    int dy=kk/7, dx=kk-dy*7;
    int pg = d_perm(h,g);
    int sy,sx; d_src(h,dy,dx,7,&sy,&sx);
    wl[idx] = Wsp[(i*8+pg)*49 + sy*7+sx];
  }
  __syncthreads();
  int pix = blockIdx.x*blockDim.x+threadIdx.x;
  if(pix>=PIX) return;
  int y=pix/HW, x=pix-y*HW;
  float acc=0.f;
  for(int i=0;i<2;i++){
    for(int g=0;g<8;g++){
      const float* pb = p + (size_t)((b*2+i)*8+g)*PIX;
      const float* wb = wl + (i*8+g)*49;
      for(int dy=0;dy<7;dy++){
        int yy=y+dy-3; if(yy<0||yy>=HW) continue;
        for(int dx=0;dx<7;dx++){
          int xx=x+dx-3; if(xx<0||xx>=HW) continue;
          acc += pb[yy*HW+xx]*wb[dy*7+dx];
        }
      }
    }
  }
  asp[(size_t)bh*PIX+pix] = 1.f/(1.f+__expf(-acc));
}

// ---------- modulate in-place: t *= a_ch[b,c,g] * a_sp[b,g,y,x] ----------
__global__ void k_mod(float4* __restrict__ t, const float* __restrict__ ach, const float4* __restrict__ asp){
  int i = blockIdx.x*blockDim.x+threadIdx.x;
  if(i>=NPIXT/4) return;
  int bcg = i/(PIX/4);
  int pix4 = i - bcg*(PIX/4);
  int b = bcg/CIN; int cg = bcg - b*CIN; int g = cg&7;
  float a1 = ach[bcg];
  float4 a2 = asp[(b*8+g)*(PIX/4) + pix4];
  float4 v = t[i];
  v.x *= a1*a2.x; v.y*=a1*a2.y; v.z*=a1*a2.z; v.w*=a1*a2.w;
  t[i]=v;
}

// ---------- transform main conv kernels into Kt[ci][co][k] (contiguous per co-tile) ----------
__global__ void k_kt(const float* __restrict__ W, float* __restrict__ Kt){
  int t = blockIdx.x*blockDim.x+threadIdx.x;
  if(t>=CIN*9) return;
  int ci = blockIdx.y;
  int co = t/9; int k = t-co*9;
  int h = co/C96; int o = co-h*C96;
  int i = ci>>3, g = ci&7;
  int pg = d_perm(h,g);
  int dy=k/3, dx=k-dy*3;
  int sy,sx; d_src(h,dy,dx,3,&sy,&sx);
  Kt[((size_t)ci*CIN+co)*9+k] = W[((o*C96+i)*8+pg)*9 + sy*3+sx];
}

// ---------- main 3x3 group conv (as dense 768->768 conv), fp32 direct ----------
// grid: (7 y-tiles, 48 co-tiles of 16, B). block: 448 = 56x * 8y.
__global__ __launch_bounds__(448) void k_conv(const float* __restrict__ in, const float* __restrict__ Kt,
        const float* __restrict__ resid, float* __restrict__ out){
  __shared__ float tile[4][10][58];
  int tid=threadIdx.x;
  int x = tid%56, yl = tid/56;
  int y0 = blockIdx.x*8;
  int co0 = blockIdx.y*16;
  int b = blockIdx.z;
  int h = co0/C96;                 // co-tiles never straddle h (96 % 16 == 0)
  float acc[16];
  #pragma unroll
  for(int j=0;j<16;j++) acc[j]=0.f;
  const float* inb = in + (size_t)b*CIN*PIX;
  for(int cc=0;cc<CIN;cc+=4){
    __syncthreads();
    for(int idx=tid; idx<2320; idx+=448){
      int cl=idx/580; int rem=idx-cl*580;
      int row=rem/58; int col=rem-row*58;
      int yy=y0-1+row, xx=col-1;
      float v=0.f;
      if(yy>=0&&yy<56&&xx>=0&&xx<56) v = inb[(size_t)(cc+cl)*PIX + yy*56+xx];
      tile[cl][row][col]=v;
    }
    __syncthreads();
    #pragma unroll
    for(int cl=0;cl<4;cl++){
      float v[9];
      #pragma unroll
      for(int dy=0;dy<3;dy++)
        #pragma unroll
        for(int dx=0;dx<3;dx++)
          v[dy*3+dx]=tile[cl][yl+dy][x+dx];
      const float* w = Kt + ((size_t)(cc+cl)*CIN + co0)*9;   // 144 consecutive floats (scalar loads)
      #pragma unroll
      for(int j=0;j<16;j++)
        #pragma unroll
        for(int k=0;k<9;k++)
          acc[j] = fmaf(w[j*9+k], v[k], acc[j]);
    }
  }
  int y=y0+yl;
  #pragma unroll
  for(int j=0;j<16;j++){
    int o = co0 - h*C96 + j;
    size_t oi = ((size_t)(b*C96+o)*8+h)*PIX + y*56+x;
    float r = resid ? resid[oi] : 0.f;
    out[oi] = acc[j] + r;
  }
}

// ---------- host side ----------
static void run_layer(const float* xin_bn, float* work, float* convout,
                      const float* W, const float* a1W, const float* a2W, const float* spW,
                      const float* bng, const float* bnb, const float* resid,
                      float* stats, float* sbuf, float* tbuf, float* ach, float* pbuf, float* asp, float* Kt,
                      hipStream_t stream)
{
  k_bn_stats<<<C96,256,0,stream>>>(xin_bn, stats);
  k_bn_relu<<<(NPIXT/4)/256,256,0,stream>>>((const float4*)xin_bn, stats, bng, bnb, (float4*)work);
  k_chan_stats<<<4*C96*NG,128,0,stream>>>(work, sbuf);
  k_ca1<<<4,NMID*8,0,stream>>>(sbuf, a1W, tbuf);
  k_ca2<<<4,C96*8,0,stream>>>(tbuf, a2W, ach);
  dim3 gsp((PIX+255)/256, 4*NG);
  k_sp_pool<<<gsp,256,0,stream>>>(work, pbuf);
  k_sp_conv<<<gsp,256,0,stream>>>(pbuf, spW, asp);
  k_mod<<<(NPIXT/4)/256,256,0,stream>>>((float4*)work, ach, (const float4*)asp);
  k_kt<<<dim3((CIN*9+255)/256, CIN),256,0,stream>>>(W, Kt);
  k_conv<<<dim3(7,48,4),448,0,stream>>>(work, Kt, resid, convout);
}

extern "C" void kernel_launch(void* const* d_in, const int* in_sizes, int n_in,
                              void* d_out, int out_size, void* d_ws, size_t ws_size,
                              hipStream_t stream) {
  const float* x    = (const float*)d_in[0];
  const float* bn1g = (const float*)d_in[1];
  const float* bn1b = (const float*)d_in[2];
  const float* bn2g = (const float*)d_in[3];
  const float* bn2b = (const float*)d_in[4];
  const float* c1W  = (const float*)d_in[5];
  const float* c1a1 = (const float*)d_in[6];
  const float* c1a2 = (const float*)d_in[7];
  const float* c1sp = (const float*)d_in[8];
  const float* c2W  = (const float*)d_in[9];
  const float* c2a1 = (const float*)d_in[10];
  const float* c2a2 = (const float*)d_in[11];
  const float* c2sp = (const float*)d_in[12];
  float* out = (float*)d_out;
  float* ws  = (float*)d_ws;

  float* bufA  = ws;                       // 9,633,792
  float* bufB  = bufA + NPIXT;             // 9,633,792
  float* Kt    = bufB + NPIXT;             // 5,308,416
  float* stats = Kt + (size_t)CIN*CIN*9;   // 192
  float* sbuf  = stats + 2*C96;            // 3072
  float* tbuf  = sbuf + 4*C96*NG;          // 1536
  float* ach   = tbuf + 4*NMID*NG;         // 3072
  float* pbuf  = ach + 4*C96*NG;           // 200,704
  float* asp   = pbuf + 4*2*NG*PIX;        // 100,352
  // total ~= 99.5 MB of workspace

  // layer 1: t1 = relu(bn(x)); attention; h1 = conv_gg(t1*att)
  run_layer(x, bufA, bufB, c1W, c1a1, c1a2, c1sp, bn1g, bn1b, nullptr,
            stats, sbuf, tbuf, ach, pbuf, asp, Kt, stream);
  // layer 2: t2 = relu(bn(h1)); attention; out = x + conv_gg(t2*att)
  run_layer(bufB, bufB, out, c2W, c2a1, c2a2, c2sp, bn2g, bn2b, x,
            stats, sbuf, tbuf, ach, pbuf, asp, Kt, stream);
}

// Round 2
// 1691.628 us; speedup vs baseline: 4.3878x; 4.3878x over previous
//
#include <hip/hip_runtime.h>
#include <math.h>

#define NG 8
#define C96 96
#define NMID 48
#define HW 56
#define PIX 3136      // 56*56
#define GHW 25088     // 8*3136
#define CIN 768       // 96*8
#define NPIXT 9633792 // 4*96*8*3136
#define BN_N 100352   // 4*8*3136
#define PADW 58
#define PADPIX 3364   // 58*58

typedef __attribute__((ext_vector_type(8))) short bf16x8;
typedef __attribute__((ext_vector_type(4))) float f32x4;

// ---------- group math (matches reference _comp/_inv/_PERM; verified round 1) ----------
__device__ __forceinline__ int d_comp(int a, int b){
  int m1=a>>2, r1=a&3, m2=b>>2, r2=b&3;
  int m=(m1+m2)&1;
  int r = (m2==0) ? (r1+r2) : (r2-r1);
  r = (r+4)&3;
  return 4*m+r;
}
__device__ __forceinline__ int d_inv(int a){ return (a>>2) ? a : ((4-(a&3))&3); }
__device__ __forceinline__ int d_perm(int h, int g){ return d_comp(d_inv(h), g); }

__device__ __forceinline__ void d_src(int h, int dy, int dx, int n, int* sy, int* sx){
  int r=h&3, m=h>>2, e=n-1;
  int y,x;
  if(r==0){y=dy; x=dx;}
  else if(r==1){y=dx; x=e-dy;}
  else if(r==2){y=e-dy; x=e-dx;}
  else {y=e-dx; x=dy;}
  if(m) x = e-x;
  *sy=y; *sx=x;
}

__device__ __forceinline__ unsigned short f2bf(float f){
  unsigned int u = __builtin_bit_cast(unsigned int, f);
  unsigned int r = (u + 0x7FFFu + ((u>>16)&1u)) >> 16;
  return (unsigned short)r;
}

// ---------- BN stats: per-channel mean/var over (B,G,H,W) ----------
__global__ void k_bn_stats(const float* __restrict__ in, float* __restrict__ stats){
  __shared__ float sm[16];
  int c = blockIdx.x;
  float s=0.f, s2=0.f;
  for (int b=0;b<4;b++){
    const float4* p = (const float4*)(in + ((size_t)(b*C96 + c))*GHW);
    for (int i=threadIdx.x; i<GHW/4; i+=blockDim.x){
      float4 v = p[i];
      s  += v.x+v.y+v.z+v.w;
      s2 += v.x*v.x+v.y*v.y+v.z*v.z+v.w*v.w;
    }
  }
  #pragma unroll
  for (int off=32; off>0; off>>=1){ s += __shfl_down(s,off); s2 += __shfl_down(s2,off); }
  int lane=threadIdx.x&63, wid=threadIdx.x>>6;
  if(lane==0){ sm[wid]=s; sm[8+wid]=s2; }
  __syncthreads();
  if(threadIdx.x==0){
    float a=0.f,b2=0.f; int nw = blockDim.x>>6;
    for(int i=0;i<nw;i++){ a+=sm[i]; b2+=sm[8+i]; }
    float mean = a/(float)BN_N;
    stats[c]=mean;
    stats[C96+c]=b2/(float)BN_N - mean*mean;
  }
}

// ---------- BN apply + ReLU ----------
__global__ void k_bn_relu(const float4* __restrict__ in, const float* __restrict__ stats,
                          const float* __restrict__ gamma, const float* __restrict__ beta,
                          float4* __restrict__ outv){
  int i = blockIdx.x*blockDim.x + threadIdx.x;
  if (i >= NPIXT/4) return;
  int c = (i / (GHW/4)) % C96;
  float mean = stats[c], var = stats[C96+c];
  float sc = gamma[c]*rsqrtf(var + 2e-5f);
  float sh = beta[c] - mean*sc;
  float4 v = in[i];
  float4 o;
  o.x = fmaxf(fmaf(v.x,sc,sh), 0.f);
  o.y = fmaxf(fmaf(v.y,sc,sh), 0.f);
  o.z = fmaxf(fmaf(v.z,sc,sh), 0.f);
  o.w = fmaxf(fmaf(v.w,sc,sh), 0.f);
  outv[i]=o;
}

// ---------- s[b,c,g] = mean_{H,W} ----------
__global__ void k_chan_stats(const float* __restrict__ t, float* __restrict__ s){
  __shared__ float sm[2];
  int bcg = blockIdx.x;
  const float4* p = (const float4*)(t + (size_t)bcg*PIX);
  float acc=0.f;
  for (int i=threadIdx.x; i<PIX/4; i+=blockDim.x){ float4 v=p[i]; acc += v.x+v.y+v.z+v.w; }
  #pragma unroll
  for(int off=32;off>0;off>>=1) acc += __shfl_down(acc,off);
  if((threadIdx.x&63)==0) sm[threadIdx.x>>6]=acc;
  __syncthreads();
  if(threadIdx.x==0) s[bcg] = (sm[0]+sm[1])/(float)PIX;
}

// ---------- channel attention stage 1 ----------
__global__ void k_ca1(const float* __restrict__ s, const float* __restrict__ W1, float* __restrict__ t){
  __shared__ float sl[CIN];
  int b = blockIdx.x;
  for (int i=threadIdx.x;i<CIN;i+=blockDim.x) sl[i]=s[b*CIN+i];
  __syncthreads();
  int m = threadIdx.x>>3, o = threadIdx.x&7;
  int pg[8];
  #pragma unroll
  for(int g=0;g<8;g++) pg[g]=d_perm(o,g);
  float acc=0.f;
  for(int c=0;c<C96;c++){
    #pragma unroll
    for(int g=0;g<8;g++) acc += W1[(m*C96+c)*8+pg[g]] * sl[c*8+g];
  }
  t[(b*NMID+m)*8+o] = fmaxf(acc,0.f);
}

// ---------- channel attention stage 2 ----------
__global__ void k_ca2(const float* __restrict__ t, const float* __restrict__ W2, float* __restrict__ a){
  __shared__ float tl[NMID*8];
  int b=blockIdx.x;
  for(int i=threadIdx.x;i<NMID*8;i+=blockDim.x) tl[i]=t[b*NMID*8+i];
  __syncthreads();
  int c=threadIdx.x>>3, o=threadIdx.x&7;
  int pg[8];
  #pragma unroll
  for(int g=0;g<8;g++) pg[g]=d_perm(o,g);
  float acc=0.f;
  for(int m=0;m<NMID;m++){
    #pragma unroll
    for(int g=0;g<8;g++) acc += W2[(c*NMID+m)*8+pg[g]] * tl[m*8+g];
  }
  a[(b*C96+c)*8+o] = 1.f/(1.f+__expf(-acc));
}

// ---------- spatial pool ----------
__global__ void k_sp_pool(const float* __restrict__ t, float* __restrict__ p){
  int pix = blockIdx.x*blockDim.x+threadIdx.x;
  if(pix>=PIX) return;
  int bg = blockIdx.y; int b=bg>>3, g=bg&7;
  const float* q = t + (size_t)b*CIN*PIX + g*PIX + pix;
  float s=0.f, mx=-1e30f;
  for(int c=0;c<C96;c++){ float v = q[(size_t)c*8*PIX]; s+=v; mx=fmaxf(mx,v); }
  p[((b*2+0)*8+g)*PIX+pix] = s/(float)C96;
  p[((b*2+1)*8+g)*PIX+pix] = mx;
}

// ---------- spatial attention 7x7 group conv + sigmoid ----------
__global__ void k_sp_conv(const float* __restrict__ p, const float* __restrict__ Wsp, float* __restrict__ asp){
  __shared__ float wl[2*8*49];
  int bh = blockIdx.y; int b=bh>>3, h=bh&7;
  for(int idx=threadIdx.x; idx<784; idx+=blockDim.x){
    int i = idx/392; int rem = idx-i*392;
    int g = rem/49; int kk = rem-g*49;
    int dy=kk/7, dx=kk-dy*7;
    int pg = d_perm(h,g);
    int sy,sx; d_src(h,dy,dx,7,&sy,&sx);
    wl[idx] = Wsp[(i*8+pg)*49 + sy*7+sx];
  }
  __syncthreads();
  int pix = blockIdx.x*blockDim.x+threadIdx.x;
  if(pix>=PIX) return;
  int y=pix/HW, x=pix-y*HW;
  float acc=0.f;
  for(int i=0;i<2;i++){
    for(int g=0;g<8;g++){
      const float* pb = p + (size_t)((b*2+i)*8+g)*PIX;
      const float* wb = wl + (i*8+g)*49;
      for(int dy=0;dy<7;dy++){
        int yy=y+dy-3; if(yy<0||yy>=HW) continue;
        for(int dx=0;dx<7;dx++){
          int xx=x+dx-3; if(xx<0||xx>=HW) continue;
          acc += pb[yy*HW+xx]*wb[dy*7+dx];
        }
      }
    }
  }
  asp[(size_t)bh*PIX+pix] = 1.f/(1.f+__expf(-acc));
}

// ---------- zero the padded NHWC input buffer (once per launch) ----------
__global__ void k_zero_xp(uint4* __restrict__ p){
  p[blockIdx.x*256 + threadIdx.x] = (uint4){0u,0u,0u,0u};
}

// ---------- fused modulate + NCHW->padded-NHWC transpose + bf16 convert ----------
// work[b][cg][pix] * ach[b][cg] * asp[b][g][pix] -> Xp[b][(y+1)*58+(x+1)][cg]
__global__ __launch_bounds__(256) void k_mod_t(const float* __restrict__ work,
    const float* __restrict__ ach, const float* __restrict__ asp,
    unsigned short* __restrict__ Xp){
  __shared__ float tile[64][65];
  int b = blockIdx.z;
  int cg0 = blockIdx.y*64;
  int pix0 = blockIdx.x*64;
  int lane = threadIdx.x & 63, w = threadIdx.x >> 6;
  for (int r = w; r < 64; r += 4){
    int cg = cg0 + r;
    float a1 = ach[b*CIN + cg];
    tile[r][lane] = work[(size_t)(b*CIN + cg)*PIX + pix0 + lane] * a1;
  }
  __syncthreads();
  for (int r = w; r < 64; r += 4){
    int pix = pix0 + r;
    int y = pix/HW, x = pix - y*HW;
    int g = lane & 7;
    float a2 = asp[(size_t)(b*8+g)*PIX + pix];
    float v = tile[lane][r] * a2;
    Xp[((size_t)b*PADPIX + (y+1)*PADW + (x+1))*CIN + cg0 + lane] = f2bf(v);
  }
}

// ---------- weight transform -> bf16 Wt[kk][co][ci] ----------
__global__ void k_ktb(const float* __restrict__ W, unsigned short* __restrict__ Wt){
  int idx = blockIdx.x*256 + threadIdx.x;   // over 9*768*768 = 5,308,416 (exact grid)
  int ci = idx % CIN;
  int t2 = idx / CIN;
  int co = t2 % CIN;
  int kk = t2 / CIN;
  int h = co/C96, o = co - h*C96;
  int i = ci >> 3, g = ci & 7;
  int dy = kk/3, dx = kk - dy*3;
  int sy, sx; d_src(h, dy, dx, 3, &sy, &sx);
  float v = W[((o*C96 + i)*8 + d_perm(h,g))*9 + sy*3 + sx];
  Wt[idx] = f2bf(v);
}

// ---------- main conv: implicit GEMM, bf16 MFMA, zero LDS ----------
// grid (28 n-tiles of 2 rows, 6 m-tiles of 128 co, 4 batch), block 256 (4 waves).
// wave w covers co0+w*32 (2 m-frags); all waves share the 7 n-frags (112 px).
__global__ __launch_bounds__(256, 3) void k_convmf(const unsigned short* __restrict__ Xp,
    const unsigned short* __restrict__ Wt, const float* __restrict__ resid,
    float* __restrict__ out){
  int tid = threadIdx.x;
  int lane = tid & 63, w = tid >> 6;
  int col = lane & 15, kg = lane >> 4;
  int y0 = blockIdx.x * 2;
  int co0 = blockIdx.y * 128;
  int b = blockIdx.z;

  const char* xb = (const char*)Xp + (size_t)b*PADPIX*CIN*2;

  int boff[7];
  #pragma unroll
  for (int nf = 0; nf < 7; nf++){
    int q = nf*16 + col;
    int yl = (q >= 56) ? 1 : 0;
    int x = q - yl*56;
    boff[nf] = (((y0 + yl)*PADW + x)*CIN + kg*8)*2;
  }
  int aoff[2];
  #pragma unroll
  for (int mf = 0; mf < 2; mf++){
    int co = co0 + w*32 + mf*16 + col;
    aoff[mf] = (co*CIN + kg*8)*2;
  }

  f32x4 acc[2][7];
  #pragma unroll
  for (int mf=0; mf<2; mf++)
    #pragma unroll
    for (int nf=0; nf<7; nf++)
      acc[mf][nf] = (f32x4){0.f,0.f,0.f,0.f};

  for (int kk = 0; kk < 9; kk++){
    const char* wb = (const char*)Wt + (size_t)kk*(CIN*CIN*2);
    int dyk = kk/3, dxk = kk - dyk*3;
    const char* xk = xb + (dyk*PADW + dxk)*(CIN*2);
    #pragma unroll 2
    for (int ci0 = 0; ci0 < CIN; ci0 += 32){
      bf16x8 a0 = *reinterpret_cast<const bf16x8*>(wb + aoff[0] + ci0*2);
      bf16x8 a1 = *reinterpret_cast<const bf16x8*>(wb + aoff[1] + ci0*2);
      #pragma unroll
      for (int nf = 0; nf < 7; nf++){
        bf16x8 bb = *reinterpret_cast<const bf16x8*>(xk + boff[nf] + ci0*2);
        acc[0][nf] = __builtin_amdgcn_mfma_f32_16x16x32_bf16(a0, bb, acc[0][nf], 0,0,0);
        acc[1][nf] = __builtin_amdgcn_mfma_f32_16x16x32_bf16(a1, bb, acc[1][nf], 0,0,0);
      }
    }
  }

  #pragma unroll
  for (int mf = 0; mf < 2; mf++){
    int co_b = co0 + w*32 + mf*16;      // uniform; 16-row block never straddles h (96%16==0)
    int h = co_b/C96;
    int ob = co_b - h*C96 + kg*4;
    #pragma unroll
    for (int nf = 0; nf < 7; nf++){
      int q = nf*16 + col;
      #pragma unroll
      for (int r = 0; r < 4; r++){
        size_t oi = ((size_t)((b*C96 + ob + r)*8 + h))*PIX + y0*56 + q;
        float v = acc[mf][nf][r];
        if (resid) v += resid[oi];
        out[oi] = v;
      }
    }
  }
}

// ---------- host side ----------
static void run_layer(const float* bn_in, float* work,
                      const float* W, const float* a1W, const float* a2W, const float* spW,
                      const float* bng, const float* bnb,
                      const float* resid, float* convout,
                      float* stats, float* sbuf, float* tbuf, float* ach, float* pbuf, float* asp,
                      unsigned short* Wt, unsigned short* Xp, hipStream_t stream)
{
  k_bn_stats<<<C96,256,0,stream>>>(bn_in, stats);
  k_bn_relu<<<(NPIXT/4)/256,256,0,stream>>>((const float4*)bn_in, stats, bng, bnb, (float4*)work);
  k_chan_stats<<<4*C96*NG,128,0,stream>>>(work, sbuf);
  k_ca1<<<4,NMID*8,0,stream>>>(sbuf, a1W, tbuf);
  k_ca2<<<4,C96*8,0,stream>>>(tbuf, a2W, ach);
  dim3 gsp((PIX+255)/256, 4*NG);
  k_sp_pool<<<gsp,256,0,stream>>>(work, pbuf);
  k_sp_conv<<<gsp,256,0,stream>>>(pbuf, spW, asp);
  k_ktb<<<(9*CIN*CIN)/256,256,0,stream>>>(W, Wt);
  k_mod_t<<<dim3(PIX/64, CIN/64, 4),256,0,stream>>>(work, ach, asp, Xp);
  k_convmf<<<dim3(28,6,4),256,0,stream>>>(Xp, Wt, resid, convout);
}

extern "C" void kernel_launch(void* const* d_in, const int* in_sizes, int n_in,
                              void* d_out, int out_size, void* d_ws, size_t ws_size,
                              hipStream_t stream) {
  const float* x    = (const float*)d_in[0];
  const float* bn1g = (const float*)d_in[1];
  const float* bn1b = (const float*)d_in[2];
  const float* bn2g = (const float*)d_in[3];
  const float* bn2b = (const float*)d_in[4];
  const float* c1W  = (const float*)d_in[5];
  const float* c1a1 = (const float*)d_in[6];
  const float* c1a2 = (const float*)d_in[7];
  const float* c1sp = (const float*)d_in[8];
  const float* c2W  = (const float*)d_in[9];
  const float* c2a1 = (const float*)d_in[10];
  const float* c2a2 = (const float*)d_in[11];
  const float* c2sp = (const float*)d_in[12];
  float* out = (float*)d_out;
  float* ws  = (float*)d_ws;

  float* bufA = ws;                                     // 9,633,792 f32
  unsigned short* Wt = (unsigned short*)(bufA + NPIXT); // 5,308,416 bf16
  unsigned short* Xp = (unsigned short*)((float*)Wt + (9*CIN*CIN)/2); // 10,334,208 bf16
  float* stats = (float*)Xp + (4*PADPIX*CIN)/2;         // 192
  float* sbuf  = stats + 2*C96;                         // 3072
  float* tbuf  = sbuf + 4*C96*NG;                       // 1536
  float* ach   = tbuf + 4*NMID*NG;                      // 3072
  float* pbuf  = ach + 4*C96*NG;                        // 200,704
  float* asp   = pbuf + 4*2*NG*PIX;                     // 100,352
  // total ~= 71 MB of workspace

  // zero padded input buffer once; pad border stays 0 for both layers
  k_zero_xp<<<(4*PADPIX*CIN*2/16)/256,256,0,stream>>>((uint4*)Xp);

  // layer 1: h1 = conv_gg(mod(relu(bn1(x)))) -> bufA
  run_layer(x, bufA, c1W, c1a1, c1a2, c1sp, bn1g, bn1b, nullptr, bufA,
            stats, sbuf, tbuf, ach, pbuf, asp, Wt, Xp, stream);
  // layer 2: out = x + conv_gg(mod(relu(bn2(h1))))
  run_layer(bufA, bufA, c2W, c2a1, c2a2, c2sp, bn2g, bn2b, x, out,
            stats, sbuf, tbuf, ach, pbuf, asp, Wt, Xp, stream);
}

// Round 3
// 877.163 us; speedup vs baseline: 8.4620x; 1.9285x over previous
//
#include <hip/hip_runtime.h>
#include <math.h>

#define NG 8
#define C96 96
#define NMID 48
#define HW 56
#define PIX 3136      // 56*56
#define GHW 25088     // 8*3136
#define CIN 768       // 96*8
#define NPIXT 9633792 // 4*96*8*3136
#define BN_N 100352   // 4*8*3136
#define PADW 58
#define PADPIX 3364   // 58*58
#define WTK 589824    // 768*768 per-tap stride in Wt

typedef __attribute__((ext_vector_type(8))) short bf16x8;
typedef __attribute__((ext_vector_type(4))) float f32x4;

// ---------- group math (verified rounds 0-2) ----------
__device__ __forceinline__ int d_comp(int a, int b){
  int m1=a>>2, r1=a&3, m2=b>>2, r2=b&3;
  int m=(m1+m2)&1;
  int r = (m2==0) ? (r1+r2) : (r2-r1);
  r = (r+4)&3;
  return 4*m+r;
}
__device__ __forceinline__ int d_inv(int a){ return (a>>2) ? a : ((4-(a&3))&3); }
__device__ __forceinline__ int d_perm(int h, int g){ return d_comp(d_inv(h), g); }

__device__ __forceinline__ void d_src(int h, int dy, int dx, int n, int* sy, int* sx){
  int r=h&3, m=h>>2, e=n-1;
  int y,x;
  if(r==0){y=dy; x=dx;}
  else if(r==1){y=dx; x=e-dy;}
  else if(r==2){y=e-dy; x=e-dx;}
  else {y=e-dx; x=dy;}
  if(m) x = e-x;
  *sy=y; *sx=x;
}

__device__ __forceinline__ unsigned short f2bf(float f){
  unsigned int u = __builtin_bit_cast(unsigned int, f);
  unsigned int r = (u + 0x7FFFu + ((u>>16)&1u)) >> 16;
  return (unsigned short)r;
}

__device__ __forceinline__ void gload_lds16(const void* g, void* l){
  __builtin_amdgcn_global_load_lds((const __attribute__((address_space(1))) unsigned int*)g,
                                   (__attribute__((address_space(3))) unsigned int*)l, 16, 0, 0);
}

// ---------- BN stats (+ zero sbuf for the fused pass) ----------
__global__ void k_bn_stats(const float* __restrict__ in, float* __restrict__ stats,
                           float* __restrict__ sbuf){
  __shared__ float sm[16];
  int c = blockIdx.x;
  if (threadIdx.x < 32){
    int b = threadIdx.x>>3, g = threadIdx.x&7;
    sbuf[(b*C96 + c)*8 + g] = 0.f;
  }
  float s=0.f, s2=0.f;
  for (int b=0;b<4;b++){
    const float4* p = (const float4*)(in + ((size_t)(b*C96 + c))*GHW);
    for (int i=threadIdx.x; i<GHW/4; i+=blockDim.x){
      float4 v = p[i];
      s  += v.x+v.y+v.z+v.w;
      s2 += v.x*v.x+v.y*v.y+v.z*v.z+v.w*v.w;
    }
  }
  #pragma unroll
  for (int off=32; off>0; off>>=1){ s += __shfl_down(s,off); s2 += __shfl_down(s2,off); }
  int lane=threadIdx.x&63, wid=threadIdx.x>>6;
  if(lane==0){ sm[wid]=s; sm[8+wid]=s2; }
  __syncthreads();
  if(threadIdx.x==0){
    float a=0.f,b2=0.f; int nw = blockDim.x>>6;
    for(int i=0;i<nw;i++){ a+=sm[i]; b2+=sm[8+i]; }
    float mean = a/(float)BN_N;
    stats[c]=mean;
    stats[C96+c]=b2/(float)BN_N - mean*mean;
  }
}

// ---------- fused: bn+relu apply, write work, channel sums (atomic), spatial mean/max ----------
// grid (7, 32): x = 448-px strip, y = (b,g). block 448.
__global__ __launch_bounds__(448) void k_fuse1(const float* __restrict__ in,
    const float* __restrict__ stats, const float* __restrict__ gamma, const float* __restrict__ beta,
    float* __restrict__ work, float* __restrict__ sbuf, float* __restrict__ pbuf){
  __shared__ float scs[C96], shs[C96];
  int tid = threadIdx.x;
  if (tid < C96){
    float mean = stats[tid], var = stats[C96+tid];
    float sc = gamma[tid]*rsqrtf(var + 2e-5f);
    scs[tid] = sc; shs[tid] = beta[tid] - mean*sc;
  }
  __syncthreads();
  int bg = blockIdx.y; int b = bg>>3, g = bg&7;
  int px = blockIdx.x*448 + tid;
  int lane = tid & 63;
  float pm = 0.f, pmx = 0.f;
  for (int c = 0; c < C96; c++){
    size_t idx = ((size_t)((b*C96 + c)*8 + g))*PIX + px;
    float v = fmaxf(fmaf(in[idx], scs[c], shs[c]), 0.f);
    work[idx] = v;
    pm += v; pmx = fmaxf(pmx, v);
    float r = v;
    #pragma unroll
    for (int off=32; off>0; off>>=1) r += __shfl_down(r, off);
    if (lane == 0) atomicAdd(&sbuf[(b*C96 + c)*8 + g], r);
  }
  pbuf[((size_t)(b*16 + g))*PIX + px] = pm;        // channel-sum (×1/96 folded into sp_conv)
  pbuf[((size_t)(b*16 + 8 + g))*PIX + px] = pmx;   // channel-max
}

// ---------- fused channel attention (ca1 + ca2) ----------
__global__ void k_ca(const float* __restrict__ sbuf, const float* __restrict__ W1,
                     const float* __restrict__ W2, float* __restrict__ ach){
  __shared__ float sl[CIN], tl[NMID*8];
  int b = blockIdx.x, tid = threadIdx.x;
  sl[tid] = sbuf[b*CIN + tid] * (1.f/3136.f);
  __syncthreads();
  int o = tid & 7;
  int pg[8];
  #pragma unroll
  for (int g=0; g<8; g++) pg[g] = d_perm(o, g);
  if (tid < NMID*8){
    int m = tid >> 3;
    float acc = 0.f;
    for (int c=0; c<C96; c++){
      #pragma unroll
      for (int g=0; g<8; g++) acc += W1[(m*C96+c)*8+pg[g]] * sl[c*8+g];
    }
    tl[tid] = fmaxf(acc, 0.f);
  }
  __syncthreads();
  {
    int c = tid >> 3;
    float acc = 0.f;
    for (int m=0; m<NMID; m++){
      #pragma unroll
      for (int g=0; g<8; g++) acc += W2[(c*NMID+m)*8+pg[g]] * tl[(m<<3)+g];
    }
    ach[b*CIN + tid] = 1.f/(1.f+__expf(-acc));
  }
}

// ---------- spatial attention 7x7 group conv + sigmoid (1/96 folded for mean slot) ----------
__global__ void k_sp_conv(const float* __restrict__ p, const float* __restrict__ Wsp, float* __restrict__ asp){
  __shared__ float wl[2*8*49];
  int bh = blockIdx.y; int b=bh>>3, h=bh&7;
  for(int idx=threadIdx.x; idx<784; idx+=blockDim.x){
    int i = idx/392; int rem = idx-i*392;
    int g = rem/49; int kk = rem-g*49;
    int dy=kk/7, dx=kk-dy*7;
    int pg = d_perm(h,g);
    int sy,sx; d_src(h,dy,dx,7,&sy,&sx);
    wl[idx] = Wsp[(i*8+pg)*49 + sy*7+sx] * (i==0 ? (1.f/96.f) : 1.f);
  }
  __syncthreads();
  int pix = blockIdx.x*blockDim.x+threadIdx.x;
  if(pix>=PIX) return;
  int y=pix/HW, x=pix-y*HW;
  float acc=0.f;
  for(int i=0;i<2;i++){
    for(int g=0;g<8;g++){
      const float* pb = p + (size_t)((b*2+i)*8+g)*PIX;
      const float* wb = wl + (i*8+g)*49;
      for(int dy=0;dy<7;dy++){
        int yy=y+dy-3; if(yy<0||yy>=HW) continue;
        for(int dx=0;dx<7;dx++){
          int xx=x+dx-3; if(xx<0||xx>=HW) continue;
          acc += pb[yy*HW+xx]*wb[dy*7+dx];
        }
      }
    }
  }
  asp[(size_t)bh*PIX+pix] = 1.f/(1.f+__expf(-acc));
}

// ---------- zero padded NHWC bf16 input ----------
__global__ void k_zero_xp(uint4* __restrict__ p){
  p[blockIdx.x*256 + threadIdx.x] = (uint4){0u,0u,0u,0u};
}

// ---------- fused modulate + NCHW->padded-NHWC transpose + bf16 (packed 4B stores) ----------
__global__ __launch_bounds__(256) void k_mod_t(const float* __restrict__ work,
    const float* __restrict__ ach, const float* __restrict__ asp,
    unsigned int* __restrict__ XpU){
  __shared__ float tile[64][65];
  int b = blockIdx.z;
  int cg0 = blockIdx.y*64;
  int pix0 = blockIdx.x*64;
  int lane = threadIdx.x & 63, w = threadIdx.x >> 6;
  for (int r = w; r < 64; r += 4){
    int cg = cg0 + r;
    float a1 = ach[b*CIN + cg];
    tile[r][lane] = work[(size_t)(b*CIN + cg)*PIX + pix0 + lane] * a1;
  }
  __syncthreads();
  int half = lane >> 5;          // 2 px per wave-iter
  int cgA = (lane & 31)*2;
  #pragma unroll
  for (int it = 0; it < 8; it++){
    int p = it*8 + w*2 + half;
    int pix = pix0 + p;
    int y = pix/HW, x = pix - y*HW;
    float aA = asp[(size_t)(b*8 + (cgA&7))*PIX + pix];
    float aB = asp[(size_t)(b*8 + ((cgA+1)&7))*PIX + pix];
    float vA = tile[cgA][p]   * aA;
    float vB = tile[cgA+1][p] * aB;
    unsigned int u = (unsigned int)f2bf(vA) | ((unsigned int)f2bf(vB) << 16);
    XpU[(((size_t)b*PADPIX + (y+1)*PADW + (x+1))*CIN + cg0 + cgA) >> 1] = u;
  }
}

// ---------- weight transform -> bf16 Wt[kk][co][ci] ----------
__global__ void k_ktb(const float* __restrict__ W, unsigned short* __restrict__ Wt){
  int idx = blockIdx.x*256 + threadIdx.x;
  int ci = idx % CIN;
  int t2 = idx / CIN;
  int co = t2 % CIN;
  int kk = t2 / CIN;
  int h = co/C96, o = co - h*C96;
  int i = ci >> 3, g = ci & 7;
  int dy = kk/3, dx = kk - dy*3;
  int sy, sx; d_src(h, dy, dx, 3, &sy, &sx);
  float v = W[((o*C96 + i)*8 + d_perm(h,g))*9 + sy*3 + sx];
  Wt[idx] = f2bf(v);
}

// ---------- main conv: implicit GEMM, LDS-pipelined bf16 MFMA ----------
// BM=128 co, BN=112 px (2 rows), K-chunk=64 ci reused across 9 taps.
// LDS: X[4 rows][64 px][64 ci] (32KB, XOR-swizzled) + W dbuf 2x[128][64] (32KB).
// grid 672 (XCD-chunked, m-major), block 256 (4 waves, wave = 32co x 112px).
__global__ __launch_bounds__(256, 2) void k_convmf(const unsigned short* __restrict__ Xp,
    const unsigned short* __restrict__ Wt, const float* __restrict__ resid,
    float* __restrict__ out){
  __shared__ unsigned short lds[32768];   // 64KB
  int tid = threadIdx.x, lane = tid & 63, w = tid >> 6;
  int col = lane & 15, kg = lane >> 4;

  int bid = blockIdx.x;
  int wgid = (bid & 7)*84 + (bid >> 3);       // bijective XCD chunking (672 = 8*84)
  int m = wgid/112; int rem = wgid - m*112;
  int b = rem/28;  int rp = rem - b*28;
  int y0 = rp*2, co0 = m*128;

  // ---- staging descriptors (ci0-independent parts) ----
  int xgo[8], xds[8];
  #pragma unroll
  for (int t = 0; t < 8; t++){
    int fg = (w*8 + t)*64 + lane;
    int row = fg >> 9;
    int pr  = (fg >> 3) & 63;
    int gi  = fg & 7;
    int sg  = gi ^ (pr & 7);
    xgo[t] = (b*PADPIX + (y0+row)*PADW + pr)*CIN + sg*8;
    xds[t] = (w*8 + t)*512;                   // wave-uniform (shorts)
  }
  int wgo[4], wds[4];
  {
    int crow = lane >> 3, gi = lane & 7, sg = gi ^ crow;
    #pragma unroll
    for (int j = 0; j < 4; j++){
      int cb = w*32 + j*8;
      wgo[j] = (co0 + cb + crow)*CIN + sg*8;
      wds[j] = 16384 + cb*64;                 // wave-uniform (shorts), + parity*8192
    }
  }
  int aidx[2][2];
  #pragma unroll
  for (int mf = 0; mf < 2; mf++)
    #pragma unroll
    for (int ks = 0; ks < 2; ks++)
      aidx[mf][ks] = (w*32 + mf*16 + col)*64 + ((((ks<<2)|kg) ^ (col&7)) << 3);

  int qx[7], qyl[7];
  #pragma unroll
  for (int nf = 0; nf < 7; nf++){
    int q = nf*16 + col;
    qyl[nf] = (q >= 56) ? 1 : 0;
    qx[nf]  = q - 56*qyl[nf];
  }

  f32x4 acc[2][7];
  #pragma unroll
  for (int mf=0; mf<2; mf++)
    #pragma unroll
    for (int nf=0; nf<7; nf++)
      acc[mf][nf] = (f32x4){0.f,0.f,0.f,0.f};

  // ---- prologue ----
  #pragma unroll
  for (int t = 0; t < 8; t++) gload_lds16(Xp + xgo[t], &lds[xds[t]]);
  #pragma unroll
  for (int j = 0; j < 4; j++) gload_lds16(Wt + wgo[j], &lds[wds[j]]);
  __syncthreads();

  int p = 0;
  for (int chunk = 0; chunk < 12; chunk++){
    int ci0 = chunk << 6;
    for (int kk = 0; kk < 9; kk++){
      int s = chunk*9 + kk;
      if (s < 107){                            // prefetch next W tap
        int nkk = (kk==8) ? 0 : kk+1;
        int nci = (kk==8) ? ci0+64 : ci0;
        size_t gofs = (size_t)nkk*WTK + nci;
        int dofs = (p^1) ? 8192 : 0;
        #pragma unroll
        for (int j = 0; j < 4; j++) gload_lds16(Wt + gofs + wgo[j], &lds[wds[j] + dofs]);
      }
      // compute tap kk from W buf p and X tile
      int dyk = kk/3, dxk = kk - dyk*3;
      const unsigned short* Wb = &lds[16384 + (p ? 8192 : 0)];
      bf16x8 A[2][2];
      #pragma unroll
      for (int mf=0; mf<2; mf++)
        #pragma unroll
        for (int ks=0; ks<2; ks++)
          A[mf][ks] = *(const bf16x8*)(Wb + aidx[mf][ks]);
      #pragma unroll
      for (int nf = 0; nf < 7; nf++){
        int t1 = qx[nf] + dxk;
        int i0 = ((qyl[nf]+dyk) << 12) | (t1 << 6) | ((kg ^ (t1 & 7)) << 3);
        bf16x8 B0 = *(const bf16x8*)(lds + i0);
        bf16x8 B1 = *(const bf16x8*)(lds + (i0 ^ 32));
        acc[0][nf] = __builtin_amdgcn_mfma_f32_16x16x32_bf16(A[0][0], B0, acc[0][nf], 0,0,0);
        acc[1][nf] = __builtin_amdgcn_mfma_f32_16x16x32_bf16(A[1][0], B0, acc[1][nf], 0,0,0);
        acc[0][nf] = __builtin_amdgcn_mfma_f32_16x16x32_bf16(A[0][1], B1, acc[0][nf], 0,0,0);
        acc[1][nf] = __builtin_amdgcn_mfma_f32_16x16x32_bf16(A[1][1], B1, acc[1][nf], 0,0,0);
      }
      __syncthreads();                         // drains W prefetch; protects buffers
      if (kk == 8 && chunk < 11){              // restage X for next ci-chunk
        #pragma unroll
        for (int t = 0; t < 8; t++) gload_lds16(Xp + xgo[t] + ci0 + 64, &lds[xds[t]]);
        __syncthreads();
      }
      p ^= 1;
    }
  }

  // ---- epilogue: NCGHW fp32 (+residual) ----
  #pragma unroll
  for (int mf = 0; mf < 2; mf++){
    int co_b = co0 + w*32 + mf*16;
    int h = co_b/C96;
    int ob = co_b - h*C96 + kg*4;
    #pragma unroll
    for (int nf = 0; nf < 7; nf++){
      int q = nf*16 + col;
      #pragma unroll
      for (int r = 0; r < 4; r++){
        size_t oi = ((size_t)((b*C96 + ob + r)*8 + h))*PIX + y0*56 + q;
        float v = acc[mf][nf][r];
        if (resid) v += resid[oi];
        out[oi] = v;
      }
    }
  }
}

// ---------- host side ----------
static void run_layer(const float* bn_in, float* work,
                      const float* a1W, const float* a2W, const float* spW,
                      const float* bng, const float* bnb,
                      const float* resid, float* convout,
                      float* stats, float* sbuf, float* ach, float* pbuf, float* asp,
                      unsigned short* Wt, unsigned short* Xp, hipStream_t stream)
{
  k_bn_stats<<<C96,256,0,stream>>>(bn_in, stats, sbuf);
  k_fuse1<<<dim3(7,32),448,0,stream>>>(bn_in, stats, bng, bnb, work, sbuf, pbuf);
  k_ca<<<4,CIN,0,stream>>>(sbuf, a1W, a2W, ach);
  k_sp_conv<<<dim3((PIX+255)/256, 32),256,0,stream>>>(pbuf, spW, asp);
  k_mod_t<<<dim3(PIX/64, CIN/64, 4),256,0,stream>>>(work, ach, asp, (unsigned int*)Xp);
  k_convmf<<<672,256,0,stream>>>(Xp, Wt, resid, convout);
}

extern "C" void kernel_launch(void* const* d_in, const int* in_sizes, int n_in,
                              void* d_out, int out_size, void* d_ws, size_t ws_size,
                              hipStream_t stream) {
  const float* x    = (const float*)d_in[0];
  const float* bn1g = (const float*)d_in[1];
  const float* bn1b = (const float*)d_in[2];
  const float* bn2g = (const float*)d_in[3];
  const float* bn2b = (const float*)d_in[4];
  const float* c1W  = (const float*)d_in[5];
  const float* c1a1 = (const float*)d_in[6];
  const float* c1a2 = (const float*)d_in[7];
  const float* c1sp = (const float*)d_in[8];
  const float* c2W  = (const float*)d_in[9];
  const float* c2a1 = (const float*)d_in[10];
  const float* c2a2 = (const float*)d_in[11];
  const float* c2sp = (const float*)d_in[12];
  float* out = (float*)d_out;
  float* ws  = (float*)d_ws;

  float* bufA = ws;                                          // 9,633,792 f32
  unsigned short* Wt1 = (unsigned short*)(bufA + NPIXT);     // 5,308,416 bf16
  unsigned short* Wt2 = Wt1 + 9*CIN*CIN;                     // 5,308,416 bf16
  unsigned short* Xp  = Wt2 + 9*CIN*CIN;                     // 10,334,208 bf16
  float* stats = (float*)(Xp + (size_t)4*PADPIX*CIN);        // 192
  float* sbuf  = stats + 2*C96;                              // 3072
  float* ach   = sbuf + 4*C96*NG;                            // 3072
  float* pbuf  = ach + 4*C96*NG;                             // 200,704
  float* asp   = pbuf + 4*2*NG*PIX;                          // 100,352
  // total ~= 82 MB

  k_ktb<<<(9*CIN*CIN)/256,256,0,stream>>>(c1W, Wt1);
  k_ktb<<<(9*CIN*CIN)/256,256,0,stream>>>(c2W, Wt2);
  k_zero_xp<<<((size_t)4*PADPIX*CIN*2/16)/256,256,0,stream>>>((uint4*)Xp);

  // layer 1: bufA = conv_gg(mod(relu(bn1(x))))
  run_layer(x, bufA, c1a1, c1a2, c1sp, bn1g, bn1b, nullptr, bufA,
            stats, sbuf, ach, pbuf, asp, Wt1, Xp, stream);
  // layer 2: out = x + conv_gg(mod(relu(bn2(bufA))))
  run_layer(bufA, bufA, c2a1, c2a2, c2sp, bn2g, bn2b, x, out,
            stats, sbuf, ach, pbuf, asp, Wt2, Xp, stream);
}

// Round 4
// 587.867 us; speedup vs baseline: 12.6263x; 1.4921x over previous
//
#include <hip/hip_runtime.h>
#include <math.h>

#define NG 8
#define C96 96
#define NMID 48
#define HW 56
#define PIX 3136      // 56*56
#define GHW 25088     // 8*3136
#define CIN 768       // 96*8
#define NPIXT 9633792 // 4*96*8*3136
#define BN_N 100352   // 4*8*3136
#define PADW 58
#define PADPIX 3364   // 58*58
#define WTK 589824    // 768*768 per-tap stride in Wt
#define PPL 3968      // padded pool plane: 62 rows x 64 cols

typedef __attribute__((ext_vector_type(8))) short bf16x8;
typedef __attribute__((ext_vector_type(4))) float f32x4;

// ---------- group math (verified rounds 0-3) ----------
__device__ __forceinline__ int d_comp(int a, int b){
  int m1=a>>2, r1=a&3, m2=b>>2, r2=b&3;
  int m=(m1+m2)&1;
  int r = (m2==0) ? (r1+r2) : (r2-r1);
  r = (r+4)&3;
  return 4*m+r;
}
__device__ __forceinline__ int d_inv(int a){ return (a>>2) ? a : ((4-(a&3))&3); }
__device__ __forceinline__ int d_perm(int h, int g){ return d_comp(d_inv(h), g); }

__device__ __forceinline__ void d_src(int h, int dy, int dx, int n, int* sy, int* sx){
  int r=h&3, m=h>>2, e=n-1;
  int y,x;
  if(r==0){y=dy; x=dx;}
  else if(r==1){y=dx; x=e-dy;}
  else if(r==2){y=e-dy; x=e-dx;}
  else {y=e-dx; x=dy;}
  if(m) x = e-x;
  *sy=y; *sx=x;
}

__device__ __forceinline__ unsigned short f2bf(float f){
  unsigned int u = __builtin_bit_cast(unsigned int, f);
  unsigned int r = (u + 0x7FFFu + ((u>>16)&1u)) >> 16;
  return (unsigned short)r;
}

__device__ __forceinline__ void gload_lds16(const void* g, void* l){
  __builtin_amdgcn_global_load_lds((const __attribute__((address_space(1))) unsigned int*)g,
                                   (__attribute__((address_space(3))) unsigned int*)l, 16, 0, 0);
}

#define VMCNT4() asm volatile("s_waitcnt vmcnt(4)" ::: "memory")
#define VMCNT0() asm volatile("s_waitcnt vmcnt(0)" ::: "memory")
#define BAR() do { __builtin_amdgcn_s_barrier(); __builtin_amdgcn_sched_barrier(0); } while(0)

// ---------- BN partial stats: grid (96 c, 8 slices), no atomics ----------
__global__ void k_bn_stats(const float* __restrict__ in, float* __restrict__ spart){
  __shared__ float sm[8];
  int c = blockIdx.x, s = blockIdx.y;
  int b = s>>1, half = s&1;
  const float4* p = (const float4*)(in + ((size_t)(b*C96 + c))*GHW) + half*(GHW/8);
  float sum=0.f, sum2=0.f;
  for (int i=threadIdx.x; i<GHW/8; i+=256){
    float4 v = p[i];
    sum  += v.x+v.y+v.z+v.w;
    sum2 += v.x*v.x+v.y*v.y+v.z*v.z+v.w*v.w;
  }
  #pragma unroll
  for (int off=32; off>0; off>>=1){ sum += __shfl_down(sum,off); sum2 += __shfl_down(sum2,off); }
  int lane=threadIdx.x&63, wid=threadIdx.x>>6;
  if(lane==0){ sm[wid]=sum; sm[4+wid]=sum2; }
  __syncthreads();
  if(threadIdx.x==0){
    float a=sm[0]+sm[1]+sm[2]+sm[3], b2=sm[4]+sm[5]+sm[6]+sm[7];
    spart[(c*8+s)*2]   = a;
    spart[(c*8+s)*2+1] = b2;
  }
}

// ---------- fused: bn+relu apply -> work, spatial mean/max -> padded pool ----------
// grid (13, 32): x = 256-px strip, y = (b,g). block 256.
__global__ __launch_bounds__(256) void k_fuse1(const float* __restrict__ in,
    const float* __restrict__ spart, const float* __restrict__ gamma, const float* __restrict__ beta,
    float* __restrict__ work, float* __restrict__ pp){
  __shared__ float scs[C96], shs[C96];
  int tid = threadIdx.x;
  if (tid < C96){
    float s=0.f, s2=0.f;
    #pragma unroll
    for (int k=0;k<8;k++){ s += spart[(tid*8+k)*2]; s2 += spart[(tid*8+k)*2+1]; }
    float mean = s*(1.f/BN_N);
    float var  = s2*(1.f/BN_N) - mean*mean;
    float sc = gamma[tid]*rsqrtf(var + 2e-5f);
    scs[tid] = sc; shs[tid] = beta[tid] - mean*sc;
  }
  __syncthreads();
  int bg = blockIdx.y; int b = bg>>3, g = bg&7;
  int px = blockIdx.x*256 + tid;
  if (px >= PIX) return;
  float pm = 0.f, pmx = 0.f;
  for (int c = 0; c < C96; c++){
    size_t idx = ((size_t)((b*C96 + c)*8 + g))*PIX + px;
    float v = fmaxf(fmaf(in[idx], scs[c], shs[c]), 0.f);
    work[idx] = v;
    pm += v; pmx = fmaxf(pmx, v);
  }
  int y = px/HW, x = px - y*HW;
  pp[(size_t)(b*16 + g)*PPL     + (y+3)*64 + (x+3)] = pm;   // sum (x 1/96 folded in sp_conv)
  pp[(size_t)(b*16 + 8 + g)*PPL + (y+3)*64 + (x+3)] = pmx;  // max
}

// ---------- channel means: s[b,c,g] = mean_px(work) ----------
__global__ void k_chan_stats(const float* __restrict__ t, float* __restrict__ s){
  int bcg = blockIdx.x;
  const float4* p = (const float4*)(t + (size_t)bcg*PIX);
  float acc=0.f;
  for (int i=threadIdx.x; i<PIX/4; i+=64){ float4 v=p[i]; acc += v.x+v.y+v.z+v.w; }
  #pragma unroll
  for(int off=32;off>0;off>>=1) acc += __shfl_down(acc,off);
  if(threadIdx.x==0) s[bcg] = acc * (1.f/3136.f);
}

// ---------- fused channel attention (ca1 + ca2) ----------
__global__ void k_ca(const float* __restrict__ sbuf, const float* __restrict__ W1,
                     const float* __restrict__ W2, float* __restrict__ ach){
  __shared__ float sl[CIN], tl[NMID*8];
  int b = blockIdx.x, tid = threadIdx.x;
  sl[tid] = sbuf[b*CIN + tid];
  __syncthreads();
  int o = tid & 7;
  int pg[8];
  #pragma unroll
  for (int g=0; g<8; g++) pg[g] = d_perm(o, g);
  if (tid < NMID*8){
    int m = tid >> 3;
    float acc = 0.f;
    for (int c=0; c<C96; c++){
      #pragma unroll
      for (int g=0; g<8; g++) acc += W1[(m*C96+c)*8+pg[g]] * sl[c*8+g];
    }
    tl[tid] = fmaxf(acc, 0.f);
  }
  __syncthreads();
  {
    int c = tid >> 3;
    float acc = 0.f;
    for (int m=0; m<NMID; m++){
      #pragma unroll
      for (int g=0; g<8; g++) acc += W2[(c*NMID+m)*8+pg[g]] * tl[(m<<3)+g];
    }
    ach[b*CIN + tid] = 1.f/(1.f+__expf(-acc));
  }
}

// ---------- spatial attention 7x7 group conv + sigmoid (branch-free, padded pool) ----------
// output transposed: aspt[b][pix][g]
__global__ __launch_bounds__(256) void k_sp_conv(const float* __restrict__ pp,
    const float* __restrict__ Wsp, float* __restrict__ aspt){
  __shared__ float wl[2*8*49];
  int bh = blockIdx.y; int b=bh>>3, h=bh&7;
  for(int idx=threadIdx.x; idx<784; idx+=256){
    int i = idx/392; int rem = idx-i*392;
    int g = rem/49; int kk = rem-g*49;
    int dy=kk/7, dx=kk-dy*7;
    int pg = d_perm(h,g);
    int sy,sx; d_src(h,dy,dx,7,&sy,&sx);
    wl[idx] = Wsp[(i*8+pg)*49 + sy*7+sx] * (i==0 ? (1.f/96.f) : 1.f);
  }
  __syncthreads();
  int pix = blockIdx.x*256 + threadIdx.x;
  if(pix>=PIX) return;
  int y=pix/HW, x=pix-y*HW;
  const float* base = pp + (size_t)(b*16)*PPL + y*64 + x;   // tap origin (pad 3 cancels -3)
  float acc=0.f;
  for(int ig=0; ig<16; ig++){
    const float* pb = base + (size_t)ig*PPL;
    const float* wb = wl + ig*49;
    #pragma unroll
    for(int dy=0; dy<7; dy++){
      #pragma unroll
      for(int dx=0; dx<7; dx++)
        acc = fmaf(pb[dy*64+dx], wb[dy*7+dx], acc);
    }
  }
  aspt[((size_t)b*PIX + pix)*8 + h] = 1.f/(1.f+__expf(-acc));
}

// ---------- zero Xp (pad borders) + pool borders ----------
__global__ void k_zero(uint4* __restrict__ xp, uint4* __restrict__ pp){
  size_t i = (size_t)blockIdx.x*256 + threadIdx.x;
  uint4 z = (uint4){0u,0u,0u,0u};
  if (i < 1291392) xp[i] = z;
  else { size_t j = i - 1291392; if (j < 63488) pp[j] = z; }
}

// ---------- fused modulate + NCHW->padded-NHWC transpose + bf16 (packed 4B stores) ----------
__global__ __launch_bounds__(256) void k_mod_t(const float* __restrict__ work,
    const float* __restrict__ ach, const float* __restrict__ aspt,
    unsigned int* __restrict__ XpU){
  __shared__ float tile[64][65];
  int b = blockIdx.z;
  int cg0 = blockIdx.y*64;
  int pix0 = blockIdx.x*64;
  int lane = threadIdx.x & 63, w = threadIdx.x >> 6;
  for (int r = w; r < 64; r += 4){
    int cg = cg0 + r;
    float a1 = ach[b*CIN + cg];
    tile[r][lane] = work[(size_t)(b*CIN + cg)*PIX + pix0 + lane] * a1;
  }
  __syncthreads();
  int half = lane >> 5;
  int cgA = (lane & 31)*2;
  #pragma unroll
  for (int it = 0; it < 8; it++){
    int p = it*8 + w*2 + half;
    int pix = pix0 + p;
    int y = pix/HW, x = pix - y*HW;
    float2 a2 = *(const float2*)(aspt + ((size_t)b*PIX + pix)*8 + (cgA&7));
    float vA = tile[cgA][p]   * a2.x;
    float vB = tile[cgA+1][p] * a2.y;
    unsigned int u = (unsigned int)f2bf(vA) | ((unsigned int)f2bf(vB) << 16);
    XpU[(((size_t)b*PADPIX + (y+1)*PADW + (x+1))*CIN + cg0 + cgA) >> 1] = u;
  }
}

// ---------- weight transform (both layers) -> bf16 Wt[kk][co][ci] ----------
__global__ void k_ktb2(const float* __restrict__ W1src, const float* __restrict__ W2src,
                       unsigned short* __restrict__ Wt1, unsigned short* __restrict__ Wt2){
  const float* W = blockIdx.y ? W2src : W1src;
  unsigned short* Wt = blockIdx.y ? Wt2 : Wt1;
  int idx = blockIdx.x*256 + threadIdx.x;
  int ci = idx % CIN;
  int t2 = idx / CIN;
  int co = t2 % CIN;
  int kk = t2 / CIN;
  int h = co/C96, o = co - h*C96;
  int i = ci >> 3, g = ci & 7;
  int dy = kk/3, dx = kk - dy*3;
  int sy, sx; d_src(h, dy, dx, 3, &sy, &sx);
  float v = W[((o*C96 + i)*8 + d_perm(h,g))*9 + sy*3 + sx];
  Wt[idx] = f2bf(v);
}

// ---------- main conv: implicit GEMM, counted-vmcnt pipelined bf16 MFMA ----------
// BM=128 co, BN=112 px (2 rows), K-chunk=64 ci reused across 9 taps.
// LDS 80KB: X [4 rows][64 px][64 ci] (32KB, XOR-swizzled) + W triple-buf 3x[128][64] (48KB).
// Per tap: A-reads -> issue W[s+2] -> MFMA -> vmcnt(4) (W[s+1] landed, W[s+2] in flight) -> barrier.
__global__ __launch_bounds__(256, 2) void k_convmf(const unsigned short* __restrict__ Xp,
    const unsigned short* __restrict__ Wt, const float* __restrict__ resid,
    float* __restrict__ out){
  __shared__ unsigned short lds[40960];   // 80KB
  int tid = threadIdx.x, lane = tid & 63, w = tid >> 6;
  int col = lane & 15, kg = lane >> 4;

  int bid = blockIdx.x;
  int wgid = (bid & 7)*84 + (bid >> 3);       // bijective XCD chunking (672 = 8*84)
  int m = wgid/112; int rem = wgid - m*112;
  int b = rem/28;  int rp = rem - b*28;
  int y0 = rp*2, co0 = m*128;

  int xgo[8], xds[8];
  #pragma unroll
  for (int t = 0; t < 8; t++){
    int fg = (w*8 + t)*64 + lane;
    int row = fg >> 9;
    int pr  = (fg >> 3) & 63;
    int gi  = fg & 7;
    int sg  = gi ^ (pr & 7);
    xgo[t] = (b*PADPIX + (y0+row)*PADW + pr)*CIN + sg*8;
    xds[t] = (w*8 + t)*512;
  }
  int wgo[4], wofs[4];
  {
    int crow = lane >> 3, gi = lane & 7, sg = gi ^ crow;
    #pragma unroll
    for (int j = 0; j < 4; j++){
      int cb = w*32 + j*8;
      wgo[j]  = (co0 + cb + crow)*CIN + sg*8;
      wofs[j] = cb*64;                        // within W buffer (shorts)
    }
  }
  int aidx[2][2];
  #pragma unroll
  for (int mf = 0; mf < 2; mf++)
    #pragma unroll
    for (int ks = 0; ks < 2; ks++)
      aidx[mf][ks] = (w*32 + mf*16 + col)*64 + ((((ks<<2)|kg) ^ (col&7)) << 3);

  int qx[7], qyl[7];
  #pragma unroll
  for (int nf = 0; nf < 7; nf++){
    int q = nf*16 + col;
    qyl[nf] = (q >= 56) ? 1 : 0;
    qx[nf]  = q - 56*qyl[nf];
  }

  f32x4 acc[2][7];
  #pragma unroll
  for (int mf=0; mf<2; mf++)
    #pragma unroll
    for (int nf=0; nf<7; nf++)
      acc[mf][nf] = (f32x4){0.f,0.f,0.f,0.f};

  // ---- prologue: W0 -> buf0, X chunk0, W1 -> buf1; wait W0+X (W1 in flight) ----
  #pragma unroll
  for (int j = 0; j < 4; j++) gload_lds16(Wt + wgo[j], &lds[16384 + wofs[j]]);
  #pragma unroll
  for (int t = 0; t < 8; t++) gload_lds16(Xp + xgo[t], &lds[xds[t]]);
  #pragma unroll
  for (int j = 0; j < 4; j++) gload_lds16(Wt + (size_t)WTK + wgo[j], &lds[16384 + 8192 + wofs[j]]);
  VMCNT4();
  BAR();

  int q = 0;
  for (int chunk = 0; chunk < 12; chunk++){
    int ci0 = chunk << 6;
    for (int kk = 0; kk < 9; kk++){
      // A-frags from W buf q
      const unsigned short* Wb = &lds[16384 + q*8192];
      bf16x8 A[2][2];
      #pragma unroll
      for (int mf=0; mf<2; mf++)
        #pragma unroll
        for (int ks=0; ks<2; ks++)
          A[mf][ks] = *(const bf16x8*)(Wb + aidx[mf][ks]);
      // issue W[s+2] into buf (q+2)%3
      int s = chunk*9 + kk;
      bool issued = (s <= 105);
      if (issued){
        int kk2 = kk + 2, c2 = chunk;
        if (kk2 >= 9){ kk2 -= 9; c2++; }
        size_t gofs = (size_t)kk2*WTK + (c2 << 6);
        int q2 = q + 2; if (q2 >= 3) q2 -= 3;
        int dofs = 16384 + q2*8192;
        #pragma unroll
        for (int j = 0; j < 4; j++) gload_lds16(Wt + gofs + wgo[j], &lds[dofs + wofs[j]]);
      }
      // MFMA cluster (B-frags float freely; X buf is stable within the chunk)
      int dyk = kk/3, dxk = kk - dyk*3;
      __builtin_amdgcn_s_setprio(1);
      #pragma unroll
      for (int nf = 0; nf < 7; nf++){
        int t1 = qx[nf] + dxk;
        int i0 = ((qyl[nf]+dyk) << 12) | (t1 << 6) | ((kg ^ (t1 & 7)) << 3);
        bf16x8 B0 = *(const bf16x8*)(lds + i0);
        bf16x8 B1 = *(const bf16x8*)(lds + (i0 ^ 32));
        acc[0][nf] = __builtin_amdgcn_mfma_f32_16x16x32_bf16(A[0][0], B0, acc[0][nf], 0,0,0);
        acc[1][nf] = __builtin_amdgcn_mfma_f32_16x16x32_bf16(A[1][0], B0, acc[1][nf], 0,0,0);
        acc[0][nf] = __builtin_amdgcn_mfma_f32_16x16x32_bf16(A[0][1], B1, acc[0][nf], 0,0,0);
        acc[1][nf] = __builtin_amdgcn_mfma_f32_16x16x32_bf16(A[1][1], B1, acc[1][nf], 0,0,0);
      }
      __builtin_amdgcn_s_setprio(0);
      // counted wait: W[s+1] landed, W[s+2] stays in flight
      if (issued) VMCNT4(); else VMCNT0();
      BAR();
      if (kk == 8 && chunk < 11){
        // all B-reads retired (consumed by MFMAs before the barrier) -> restage X
        #pragma unroll
        for (int t = 0; t < 8; t++) gload_lds16(Xp + xgo[t] + ci0 + 64, &lds[xds[t]]);
        VMCNT0();
        BAR();
      }
      q = (q+1 == 3) ? 0 : q+1;
    }
  }

  // ---- epilogue: NCGHW fp32 (+residual) ----
  #pragma unroll
  for (int mf = 0; mf < 2; mf++){
    int co_b = co0 + w*32 + mf*16;
    int h = co_b/C96;
    int ob = co_b - h*C96 + kg*4;
    #pragma unroll
    for (int nf = 0; nf < 7; nf++){
      int qq = nf*16 + col;
      #pragma unroll
      for (int r = 0; r < 4; r++){
        size_t oi = ((size_t)((b*C96 + ob + r)*8 + h))*PIX + y0*56 + qq;
        float v = acc[mf][nf][r];
        if (resid) v += resid[oi];
        out[oi] = v;
      }
    }
  }
}

// ---------- host side ----------
static void run_layer(const float* bn_in, float* work,
                      const float* a1W, const float* a2W, const float* spW,
                      const float* bng, const float* bnb,
                      const float* resid, float* convout,
                      float* spart, float* sbuf, float* ach, float* ppP, float* aspt,
                      unsigned short* Wt, unsigned short* Xp, hipStream_t stream)
{
  k_bn_stats<<<dim3(C96,8),256,0,stream>>>(bn_in, spart);
  k_fuse1<<<dim3(13,32),256,0,stream>>>(bn_in, spart, bng, bnb, work, ppP);
  k_chan_stats<<<4*C96*NG,64,0,stream>>>(work, sbuf);
  k_ca<<<4,CIN,0,stream>>>(sbuf, a1W, a2W, ach);
  k_sp_conv<<<dim3(13,32),256,0,stream>>>(ppP, spW, aspt);
  k_mod_t<<<dim3(PIX/64, CIN/64, 4),256,0,stream>>>(work, ach, aspt, (unsigned int*)Xp);
  k_convmf<<<672,256,0,stream>>>(Xp, Wt, resid, convout);
}

extern "C" void kernel_launch(void* const* d_in, const int* in_sizes, int n_in,
                              void* d_out, int out_size, void* d_ws, size_t ws_size,
                              hipStream_t stream) {
  const float* x    = (const float*)d_in[0];
  const float* bn1g = (const float*)d_in[1];
  const float* bn1b = (const float*)d_in[2];
  const float* bn2g = (const float*)d_in[3];
  const float* bn2b = (const float*)d_in[4];
  const float* c1W  = (const float*)d_in[5];
  const float* c1a1 = (const float*)d_in[6];
  const float* c1a2 = (const float*)d_in[7];
  const float* c1sp = (const float*)d_in[8];
  const float* c2W  = (const float*)d_in[9];
  const float* c2a1 = (const float*)d_in[10];
  const float* c2a2 = (const float*)d_in[11];
  const float* c2sp = (const float*)d_in[12];
  float* out = (float*)d_out;
  float* ws  = (float*)d_ws;

  float* bufA = ws;                                          // 9,633,792 f32
  unsigned short* Wt1 = (unsigned short*)(bufA + NPIXT);     // 5,308,416 bf16
  unsigned short* Wt2 = Wt1 + 9*CIN*CIN;                     // 5,308,416 bf16
  unsigned short* Xp  = Wt2 + 9*CIN*CIN;                     // 10,334,208 bf16
  float* spart = (float*)(Xp + (size_t)4*PADPIX*CIN);        // 1536
  float* sbuf  = spart + 1536;                               // 3072
  float* ach   = sbuf + 4*C96*NG;                            // 3072
  float* ppP   = ach + 4*C96*NG;                             // 253,952 (padded pool)
  float* aspt  = ppP + 4*16*PPL;                             // 100,352
  // total ~= 83 MB

  k_ktb2<<<dim3((9*CIN*CIN)/256, 2),256,0,stream>>>(c1W, c2W, Wt1, Wt2);
  k_zero<<<5293,256,0,stream>>>((uint4*)Xp, (uint4*)ppP);

  // layer 1: bufA = conv_gg(mod(relu(bn1(x))))
  run_layer(x, bufA, c1a1, c1a2, c1sp, bn1g, bn1b, nullptr, bufA,
            spart, sbuf, ach, ppP, aspt, Wt1, Xp, stream);
  // layer 2: out = x + conv_gg(mod(relu(bn2(bufA))))
  run_layer(bufA, bufA, c2a1, c2a2, c2sp, bn2g, bn2b, x, out,
            spart, sbuf, ach, ppP, aspt, Wt2, Xp, stream);
}

// Round 5
// 556.026 us; speedup vs baseline: 13.3493x; 1.0573x over previous
//
#include <hip/hip_runtime.h>
#include <math.h>

#define NG 8
#define C96 96
#define NMID 48
#define HW 56
#define PIX 3136      // 56*56
#define GHW 25088     // 8*3136
#define CIN 768       // 96*8
#define NPIXT 9633792 // 4*96*8*3136
#define BN_N 100352   // 4*8*3136
#define PADW 58
#define PADPIX 3364   // 58*58
#define WTK 589824    // 768*768 per-tap stride in Wt
#define PPL 3968      // padded pool plane: 62 rows x 64 cols

typedef __attribute__((ext_vector_type(8))) short bf16x8;
typedef __attribute__((ext_vector_type(4))) float f32x4;

// ---------- group math (verified rounds 0-4) ----------
__device__ __forceinline__ int d_comp(int a, int b){
  int m1=a>>2, r1=a&3, m2=b>>2, r2=b&3;
  int m=(m1+m2)&1;
  int r = (m2==0) ? (r1+r2) : (r2-r1);
  r = (r+4)&3;
  return 4*m+r;
}
__device__ __forceinline__ int d_inv(int a){ return (a>>2) ? a : ((4-(a&3))&3); }
__device__ __forceinline__ int d_perm(int h, int g){ return d_comp(d_inv(h), g); }

__device__ __forceinline__ void d_src(int h, int dy, int dx, int n, int* sy, int* sx){
  int r=h&3, m=h>>2, e=n-1;
  int y,x;
  if(r==0){y=dy; x=dx;}
  else if(r==1){y=dx; x=e-dy;}
  else if(r==2){y=e-dy; x=e-dx;}
  else {y=e-dx; x=dy;}
  if(m) x = e-x;
  *sy=y; *sx=x;
}

__device__ __forceinline__ unsigned short f2bf(float f){
  unsigned int u = __builtin_bit_cast(unsigned int, f);
  unsigned int r = (u + 0x7FFFu + ((u>>16)&1u)) >> 16;
  return (unsigned short)r;
}

__device__ __forceinline__ void gload_lds16(const void* g, void* l){
  __builtin_amdgcn_global_load_lds((const __attribute__((address_space(1))) unsigned int*)g,
                                   (__attribute__((address_space(3))) unsigned int*)l, 16, 0, 0);
}

#define VMCNT0() asm volatile("s_waitcnt vmcnt(0)" ::: "memory")
#define BAR() do { __builtin_amdgcn_s_barrier(); __builtin_amdgcn_sched_barrier(0); } while(0)

// ---------- BN partial stats: grid (96 c, 8 slices), no atomics ----------
__global__ void k_bn_stats(const float* __restrict__ in, float* __restrict__ spart){
  __shared__ float sm[8];
  int c = blockIdx.x, s = blockIdx.y;
  int b = s>>1, half = s&1;
  const float4* p = (const float4*)(in + ((size_t)(b*C96 + c))*GHW) + half*(GHW/8);
  float sum=0.f, sum2=0.f;
  for (int i=threadIdx.x; i<GHW/8; i+=256){
    float4 v = p[i];
    sum  += v.x+v.y+v.z+v.w;
    sum2 += v.x*v.x+v.y*v.y+v.z*v.z+v.w*v.w;
  }
  #pragma unroll
  for (int off=32; off>0; off>>=1){ sum += __shfl_down(sum,off); sum2 += __shfl_down(sum2,off); }
  int lane=threadIdx.x&63, wid=threadIdx.x>>6;
  if(lane==0){ sm[wid]=sum; sm[4+wid]=sum2; }
  __syncthreads();
  if(threadIdx.x==0){
    float a=sm[0]+sm[1]+sm[2]+sm[3], b2=sm[4]+sm[5]+sm[6]+sm[7];
    spart[(c*8+s)*2]   = a;
    spart[(c*8+s)*2+1] = b2;
  }
}

// ---------- fused: bn+relu apply -> work, spatial mean/max -> padded pool ----------
__global__ __launch_bounds__(256) void k_fuse1(const float* __restrict__ in,
    const float* __restrict__ spart, const float* __restrict__ gamma, const float* __restrict__ beta,
    float* __restrict__ work, float* __restrict__ pp){
  __shared__ float scs[C96], shs[C96];
  int tid = threadIdx.x;
  if (tid < C96){
    float s=0.f, s2=0.f;
    #pragma unroll
    for (int k=0;k<8;k++){ s += spart[(tid*8+k)*2]; s2 += spart[(tid*8+k)*2+1]; }
    float mean = s*(1.f/BN_N);
    float var  = s2*(1.f/BN_N) - mean*mean;
    float sc = gamma[tid]*rsqrtf(var + 2e-5f);
    scs[tid] = sc; shs[tid] = beta[tid] - mean*sc;
  }
  __syncthreads();
  int bg = blockIdx.y; int b = bg>>3, g = bg&7;
  int px = blockIdx.x*256 + tid;
  if (px >= PIX) return;
  float pm = 0.f, pmx = 0.f;
  for (int c = 0; c < C96; c++){
    size_t idx = ((size_t)((b*C96 + c)*8 + g))*PIX + px;
    float v = fmaxf(fmaf(in[idx], scs[c], shs[c]), 0.f);
    work[idx] = v;
    pm += v; pmx = fmaxf(pmx, v);
  }
  int y = px/HW, x = px - y*HW;
  pp[(size_t)(b*16 + g)*PPL     + (y+3)*64 + (x+3)] = pm;
  pp[(size_t)(b*16 + 8 + g)*PPL + (y+3)*64 + (x+3)] = pmx;
}

// ---------- channel means ----------
__global__ void k_chan_stats(const float* __restrict__ t, float* __restrict__ s){
  int bcg = blockIdx.x;
  const float4* p = (const float4*)(t + (size_t)bcg*PIX);
  float acc=0.f;
  for (int i=threadIdx.x; i<PIX/4; i+=64){ float4 v=p[i]; acc += v.x+v.y+v.z+v.w; }
  #pragma unroll
  for(int off=32;off>0;off>>=1) acc += __shfl_down(acc,off);
  if(threadIdx.x==0) s[bcg] = acc * (1.f/3136.f);
}

// ---------- fused channel attention (ca1 + ca2) ----------
__global__ void k_ca(const float* __restrict__ sbuf, const float* __restrict__ W1,
                     const float* __restrict__ W2, float* __restrict__ ach){
  __shared__ float sl[CIN], tl[NMID*8];
  int b = blockIdx.x, tid = threadIdx.x;
  sl[tid] = sbuf[b*CIN + tid];
  __syncthreads();
  int o = tid & 7;
  int pg[8];
  #pragma unroll
  for (int g=0; g<8; g++) pg[g] = d_perm(o, g);
  if (tid < NMID*8){
    int m = tid >> 3;
    float acc = 0.f;
    for (int c=0; c<C96; c++){
      #pragma unroll
      for (int g=0; g<8; g++) acc += W1[(m*C96+c)*8+pg[g]] * sl[c*8+g];
    }
    tl[tid] = fmaxf(acc, 0.f);
  }
  __syncthreads();
  {
    int c = tid >> 3;
    float acc = 0.f;
    for (int m=0; m<NMID; m++){
      #pragma unroll
      for (int g=0; g<8; g++) acc += W2[(c*NMID+m)*8+pg[g]] * tl[(m<<3)+g];
    }
    ach[b*CIN + tid] = 1.f/(1.f+__expf(-acc));
  }
}

// ---------- spatial attention 7x7 group conv + sigmoid (branch-free) ----------
__global__ __launch_bounds__(256) void k_sp_conv(const float* __restrict__ pp,
    const float* __restrict__ Wsp, float* __restrict__ aspt){
  __shared__ float wl[2*8*49];
  int bh = blockIdx.y; int b=bh>>3, h=bh&7;
  for(int idx=threadIdx.x; idx<784; idx+=256){
    int i = idx/392; int rem = idx-i*392;
    int g = rem/49; int kk = rem-g*49;
    int dy=kk/7, dx=kk-dy*7;
    int pg = d_perm(h,g);
    int sy,sx; d_src(h,dy,dx,7,&sy,&sx);
    wl[idx] = Wsp[(i*8+pg)*49 + sy*7+sx] * (i==0 ? (1.f/96.f) : 1.f);
  }
  __syncthreads();
  int pix = blockIdx.x*256 + threadIdx.x;
  if(pix>=PIX) return;
  int y=pix/HW, x=pix-y*HW;
  const float* base = pp + (size_t)(b*16)*PPL + y*64 + x;
  float acc=0.f;
  for(int ig=0; ig<16; ig++){
    const float* pb = base + (size_t)ig*PPL;
    const float* wb = wl + ig*49;
    #pragma unroll
    for(int dy=0; dy<7; dy++){
      #pragma unroll
      for(int dx=0; dx<7; dx++)
        acc = fmaf(pb[dy*64+dx], wb[dy*7+dx], acc);
    }
  }
  aspt[((size_t)b*PIX + pix)*8 + h] = 1.f/(1.f+__expf(-acc));
}

// ---------- zero Xp + pool borders ----------
__global__ void k_zero(uint4* __restrict__ xp, uint4* __restrict__ pp){
  size_t i = (size_t)blockIdx.x*256 + threadIdx.x;
  uint4 z = (uint4){0u,0u,0u,0u};
  if (i < 1291392) xp[i] = z;
  else { size_t j = i - 1291392; if (j < 63488) pp[j] = z; }
}

// ---------- fused modulate + transpose + bf16 pack ----------
__global__ __launch_bounds__(256) void k_mod_t(const float* __restrict__ work,
    const float* __restrict__ ach, const float* __restrict__ aspt,
    unsigned int* __restrict__ XpU){
  __shared__ float tile[64][65];
  int b = blockIdx.z;
  int cg0 = blockIdx.y*64;
  int pix0 = blockIdx.x*64;
  int lane = threadIdx.x & 63, w = threadIdx.x >> 6;
  for (int r = w; r < 64; r += 4){
    int cg = cg0 + r;
    float a1 = ach[b*CIN + cg];
    tile[r][lane] = work[(size_t)(b*CIN + cg)*PIX + pix0 + lane] * a1;
  }
  __syncthreads();
  int half = lane >> 5;
  int cgA = (lane & 31)*2;
  #pragma unroll
  for (int it = 0; it < 8; it++){
    int p = it*8 + w*2 + half;
    int pix = pix0 + p;
    int y = pix/HW, x = pix - y*HW;
    float2 a2 = *(const float2*)(aspt + ((size_t)b*PIX + pix)*8 + (cgA&7));
    float vA = tile[cgA][p]   * a2.x;
    float vB = tile[cgA+1][p] * a2.y;
    unsigned int u = (unsigned int)f2bf(vA) | ((unsigned int)f2bf(vB) << 16);
    XpU[(((size_t)b*PADPIX + (y+1)*PADW + (x+1))*CIN + cg0 + cgA) >> 1] = u;
  }
}

// ---------- weight transform (both layers) ----------
__global__ void k_ktb2(const float* __restrict__ W1src, const float* __restrict__ W2src,
                       unsigned short* __restrict__ Wt1, unsigned short* __restrict__ Wt2){
  const float* W = blockIdx.y ? W2src : W1src;
  unsigned short* Wt = blockIdx.y ? Wt2 : Wt1;
  int idx = blockIdx.x*256 + threadIdx.x;
  int ci = idx % CIN;
  int t2 = idx / CIN;
  int co = t2 % CIN;
  int kk = t2 / CIN;
  int h = co/C96, o = co - h*C96;
  int i = ci >> 3, g = ci & 7;
  int dy = kk/3, dx = kk - dy*3;
  int sy, sx; d_src(h, dy, dx, 3, &sy, &sx);
  float v = W[((o*C96 + i)*8 + d_perm(h,g))*9 + sy*3 + sx];
  Wt[idx] = f2bf(v);
}

// ---------- main conv: implicit GEMM, bf16 MFMA ----------
// BM=192 co, BN=112 px (2 rows), K-chunk=64 ci reused across 9 taps.
// 4 waves, wave tile 48co x 112px (3 m-frags x 7 n-frags) -> MFMA-bound (not LDS-read-bound).
// LDS 80KB: X [4 rows][64 px][64 ci] (32KB, XOR-swizzled) + W dbuf 2x[192][64] (48KB).
// grid 448 = 8*56 XCD-chunked (one W m-slice per XCD -> L2-resident), 2 blocks/CU.
__global__ __launch_bounds__(256, 2) void k_convmf(const unsigned short* __restrict__ Xp,
    const unsigned short* __restrict__ Wt, const float* __restrict__ resid,
    float* __restrict__ out){
  __shared__ unsigned short lds[40960];   // 80KB: X [0,16384), W [16384, 40960)
  int tid = threadIdx.x, lane = tid & 63, w = tid >> 6;
  int col = lane & 15, kg = lane >> 4;

  int bid = blockIdx.x;
  int wgid = (bid & 7)*56 + (bid >> 3);       // bijective XCD chunking (448 = 8*56)
  int m = wgid/112; int rem = wgid - m*112;
  int b = rem/28;  int rp = rem - b*28;
  int y0 = rp*2, co0 = m*192;

  int xgo[8], xds[8];
  #pragma unroll
  for (int t = 0; t < 8; t++){
    int fg = (w*8 + t)*64 + lane;
    int row = fg >> 9;
    int pr  = (fg >> 3) & 63;
    int gi  = fg & 7;
    int sg  = gi ^ (pr & 7);
    xgo[t] = (b*PADPIX + (y0+row)*PADW + pr)*CIN + sg*8;
    xds[t] = (w*8 + t)*512;
  }
  int wgo[6], wofs[6];
  {
    int crow = lane >> 3, gi = lane & 7, sg = gi ^ crow;
    #pragma unroll
    for (int j = 0; j < 6; j++){
      int cb = w*48 + j*8;
      wgo[j]  = (co0 + cb + crow)*CIN + sg*8;
      wofs[j] = cb*64;                        // within W buffer (shorts)
    }
  }
  int aidx[3][2];
  #pragma unroll
  for (int mf = 0; mf < 3; mf++)
    #pragma unroll
    for (int ks = 0; ks < 2; ks++)
      aidx[mf][ks] = (w*48 + mf*16 + col)*64 + ((((ks<<2)|kg) ^ (col&7)) << 3);

  int qx[7], qyl[7];
  #pragma unroll
  for (int nf = 0; nf < 7; nf++){
    int q = nf*16 + col;
    qyl[nf] = (q >= 56) ? 1 : 0;
    qx[nf]  = q - 56*qyl[nf];
  }

  f32x4 acc[3][7];
  #pragma unroll
  for (int mf=0; mf<3; mf++)
    #pragma unroll
    for (int nf=0; nf<7; nf++)
      acc[mf][nf] = (f32x4){0.f,0.f,0.f,0.f};

  // ---- prologue: W0 -> buf0, X chunk0; full drain ----
  #pragma unroll
  for (int j = 0; j < 6; j++) gload_lds16(Wt + wgo[j], &lds[16384 + wofs[j]]);
  #pragma unroll
  for (int t = 0; t < 8; t++) gload_lds16(Xp + xgo[t], &lds[xds[t]]);
  VMCNT0();
  BAR();

  int q = 0;
  for (int chunk = 0; chunk < 12; chunk++){
    int ci0 = chunk << 6;
    for (int kk = 0; kk < 9; kk++){
      int s = chunk*9 + kk;
      // A-frags from W buf q
      const unsigned short* Wb = &lds[16384 + q*12288];
      bf16x8 A[3][2];
      #pragma unroll
      for (int mf=0; mf<3; mf++)
        #pragma unroll
        for (int ks=0; ks<2; ks++)
          A[mf][ks] = *(const bf16x8*)(Wb + aidx[mf][ks]);
      // issue W[s+1] into buf q^1 (latency hides under the 42-MFMA cluster)
      if (s <= 106){
        int kk2 = kk + 1, c2 = chunk;
        if (kk2 == 9){ kk2 = 0; c2++; }
        size_t gofs = (size_t)kk2*WTK + (c2 << 6);
        int dofs = 16384 + (q^1)*12288;
        #pragma unroll
        for (int j = 0; j < 6; j++) gload_lds16(Wt + gofs + wgo[j], &lds[dofs + wofs[j]]);
      }
      // MFMA cluster
      int dyk = kk/3, dxk = kk - dyk*3;
      __builtin_amdgcn_s_setprio(1);
      #pragma unroll
      for (int nf = 0; nf < 7; nf++){
        int t1 = qx[nf] + dxk;
        int i0 = ((qyl[nf]+dyk) << 12) | (t1 << 6) | ((kg ^ (t1 & 7)) << 3);
        bf16x8 B0 = *(const bf16x8*)(lds + i0);
        bf16x8 B1 = *(const bf16x8*)(lds + (i0 ^ 32));
        acc[0][nf] = __builtin_amdgcn_mfma_f32_16x16x32_bf16(A[0][0], B0, acc[0][nf], 0,0,0);
        acc[1][nf] = __builtin_amdgcn_mfma_f32_16x16x32_bf16(A[1][0], B0, acc[1][nf], 0,0,0);
        acc[2][nf] = __builtin_amdgcn_mfma_f32_16x16x32_bf16(A[2][0], B0, acc[2][nf], 0,0,0);
        acc[0][nf] = __builtin_amdgcn_mfma_f32_16x16x32_bf16(A[0][1], B1, acc[0][nf], 0,0,0);
        acc[1][nf] = __builtin_amdgcn_mfma_f32_16x16x32_bf16(A[1][1], B1, acc[1][nf], 0,0,0);
        acc[2][nf] = __builtin_amdgcn_mfma_f32_16x16x32_bf16(A[2][1], B1, acc[2][nf], 0,0,0);
      }
      __builtin_amdgcn_s_setprio(0);
      VMCNT0();                                // W[s+1] landed (issued ~42 MFMAs ago)
      BAR();
      if (kk == 8 && chunk < 11){
        #pragma unroll
        for (int t = 0; t < 8; t++) gload_lds16(Xp + xgo[t] + ci0 + 64, &lds[xds[t]]);
        VMCNT0();
        BAR();
      }
      q ^= 1;
    }
  }

  // ---- epilogue: NCGHW fp32 (+residual) ----
  #pragma unroll
  for (int mf = 0; mf < 3; mf++){
    int co_b = co0 + w*48 + mf*16;             // 16-aligned, never straddles h
    int h = co_b/C96;
    int ob = co_b - h*C96 + kg*4;
    #pragma unroll
    for (int nf = 0; nf < 7; nf++){
      int qq = nf*16 + col;
      #pragma unroll
      for (int r = 0; r < 4; r++){
        size_t oi = ((size_t)((b*C96 + ob + r)*8 + h))*PIX + y0*56 + qq;
        float v = acc[mf][nf][r];
        if (resid) v += resid[oi];
        out[oi] = v;
      }
    }
  }
}

// ---------- host side ----------
static void run_layer(const float* bn_in, float* work,
                      const float* a1W, const float* a2W, const float* spW,
                      const float* bng, const float* bnb,
                      const float* resid, float* convout,
                      float* spart, float* sbuf, float* ach, float* ppP, float* aspt,
                      unsigned short* Wt, unsigned short* Xp, hipStream_t stream)
{
  k_bn_stats<<<dim3(C96,8),256,0,stream>>>(bn_in, spart);
  k_fuse1<<<dim3(13,32),256,0,stream>>>(bn_in, spart, bng, bnb, work, ppP);
  k_chan_stats<<<4*C96*NG,64,0,stream>>>(work, sbuf);
  k_ca<<<4,CIN,0,stream>>>(sbuf, a1W, a2W, ach);
  k_sp_conv<<<dim3(13,32),256,0,stream>>>(ppP, spW, aspt);
  k_mod_t<<<dim3(PIX/64, CIN/64, 4),256,0,stream>>>(work, ach, aspt, (unsigned int*)Xp);
  k_convmf<<<448,256,0,stream>>>(Xp, Wt, resid, convout);
}

extern "C" void kernel_launch(void* const* d_in, const int* in_sizes, int n_in,
                              void* d_out, int out_size, void* d_ws, size_t ws_size,
                              hipStream_t stream) {
  const float* x    = (const float*)d_in[0];
  const float* bn1g = (const float*)d_in[1];
  const float* bn1b = (const float*)d_in[2];
  const float* bn2g = (const float*)d_in[3];
  const float* bn2b = (const float*)d_in[4];
  const float* c1W  = (const float*)d_in[5];
  const float* c1a1 = (const float*)d_in[6];
  const float* c1a2 = (const float*)d_in[7];
  const float* c1sp = (const float*)d_in[8];
  const float* c2W  = (const float*)d_in[9];
  const float* c2a1 = (const float*)d_in[10];
  const float* c2a2 = (const float*)d_in[11];
  const float* c2sp = (const float*)d_in[12];
  float* out = (float*)d_out;
  float* ws  = (float*)d_ws;

  float* bufA = ws;                                          // 9,633,792 f32
  unsigned short* Wt1 = (unsigned short*)(bufA + NPIXT);     // 5,308,416 bf16
  unsigned short* Wt2 = Wt1 + 9*CIN*CIN;                     // 5,308,416 bf16
  unsigned short* Xp  = Wt2 + 9*CIN*CIN;                     // 10,334,208 bf16
  float* spart = (float*)(Xp + (size_t)4*PADPIX*CIN);        // 1536
  float* sbuf  = spart + 1536;                               // 3072
  float* ach   = sbuf + 4*C96*NG;                            // 3072
  float* ppP   = ach + 4*C96*NG;                             // 253,952 (padded pool)
  float* aspt  = ppP + 4*16*PPL;                             // 100,352
  // total ~= 83 MB

  k_ktb2<<<dim3((9*CIN*CIN)/256, 2),256,0,stream>>>(c1W, c2W, Wt1, Wt2);
  k_zero<<<5293,256,0,stream>>>((uint4*)Xp, (uint4*)ppP);

  // layer 1: bufA = conv_gg(mod(relu(bn1(x))))
  run_layer(x, bufA, c1a1, c1a2, c1sp, bn1g, bn1b, nullptr, bufA,
            spart, sbuf, ach, ppP, aspt, Wt1, Xp, stream);
  // layer 2: out = x + conv_gg(mod(relu(bn2(bufA))))
  run_layer(bufA, bufA, c2a1, c2a2, c2sp, bn2g, bn2b, x, out,
            spart, sbuf, ach, ppP, aspt, Wt2, Xp, stream);
}